// Round 8
// baseline (5433.844 us; speedup 1.0000x reference)
//
#include <hip/hip_runtime.h>
#include <cstdint>
#include <cstddef>

#define TT 256
#define NN 4096
#define CC 12
#define DD 256
#define KD 12
#define NB 8     // batch rows per block -> 512 blocks -> 2 blocks/CU
#define NTH 512
#define HS 264   // halfs per combined-plane row: 256 + 8 pad
#define XS 40    // halfs per x row: 32 + 8 pad
#define YS 20    // floats per part2 row: 16 + 4 pad

typedef _Float16 half8 __attribute__((ext_vector_type(8)));
typedef __fp16 fp16x2 __attribute__((ext_vector_type(2)));
typedef float f32x4 __attribute__((ext_vector_type(4)));
#define MFMA __builtin_amdgcn_mfma_f32_16x16x32_f16

struct FalseC { static constexpr bool value = false; };
struct TrueC  { static constexpr bool value = true;  };

// Combined hi/lo A-tile: rows 0-7 = hi(batch rows 0-7), rows 8-15 = lo(same).
// LDS: 16,896 (h) + 5,120 (x) + 10,240 (part2) = 32,256 B -> 2 blocks/CU.
struct alignas(16) SM {
  _Float16 hcomb[2][16][HS];     // h combined plane, double-buffered
  _Float16 xcomb[4][16][XS];     // x_t slots (combined hi/lo), 4-deep
  float    part2[2][8][NB][YS];  // decoder y partials [buf][wave][row][class]
};

__device__ __forceinline__ void split8(const float* w, half8& hi, half8& lo) {
  #pragma unroll
  for (int j = 0; j < 8; ++j) {
    _Float16 h = (_Float16)w[j];
    hi[j] = h;
    lo[j] = (_Float16)(w[j] - (float)h);
  }
}

// packed hi/lo split: pkrtz(v0,v1) -> hi word; lo = v - f32(hi) -> lo word
__device__ __forceinline__ void packpair(float v0, float v1,
                                         unsigned& hw, unsigned& lw) {
  union { fp16x2 v; unsigned u; } a, b;
  a.v = __builtin_amdgcn_cvt_pkrtz(v0, v1);
  const float r0 = (float)a.v[0], r1 = (float)a.v[1];
  b.v = __builtin_amdgcn_cvt_pkrtz(v0 - r0, v1 - r1);
  hw = a.u; lw = b.u;
}

// Raw barrier, R1-proven form: drain LDS only (global ops stay in flight),
// builtin convergent s_barrier, sched_barrier pins order (rule #18).
__device__ __forceinline__ void BAR() {
  asm volatile("s_waitcnt lgkmcnt(0)" ::: "memory");
  __builtin_amdgcn_s_barrier();
  __builtin_amdgcn_sched_barrier(0);
}

__global__ __launch_bounds__(NTH, 4)
void seq2seq_kernel(const float* __restrict__ x,
                    const float* __restrict__ enc_Wx,
                    const float* __restrict__ enc_bx,
                    const float* __restrict__ enc_Wh,
                    const float* __restrict__ dec_Wx,
                    const float* __restrict__ dec_bx,
                    const float* __restrict__ dec_Wh,
                    const float* __restrict__ dec_Wy,
                    const float* __restrict__ dec_by,
                    float* __restrict__ out)
{
  __shared__ SM sm;
  const int tid  = (int)threadIdx.x;
  const int wid  = tid >> 6;
  const int lane = tid & 63;
  const int l15  = lane & 15;
  const int quad = lane >> 4;
  const int n0   = (int)blockIdx.x * NB;

  half8 Whi[2][8], Wlo[2][8];   // Wh B-fragments (reg-resident), persistent
  half8 Xhi[2], Xlo[2];         // Wx B-fragments (K=32 padded chunk)
  float bxr[2];
  // prefetch regs for one 8x12 x-slab (96 floats): lane + (lane<32: lane+64)
  float pfA0 = 0.f, pfA1 = 0.f;
  float pfB0 = 0.f, pfB1 = 0.f;
  // two accumulator sets: cur carries this step's x-term (pre-accumulated),
  // nxt receives next step's x-term pre-barrier.
  f32x4 accP[4], accQ[4];

  // B column mapping: n = wid*32 + 2*l15 + tt (lane's two cols adjacent ->
  // packed b32 h-writes).
  auto loadWh = [&](const float* __restrict__ W) {
    #pragma unroll
    for (int tt = 0; tt < 2; ++tt) {
      const int n = wid * 32 + 2 * l15 + tt;
      #pragma unroll
      for (int c = 0; c < 8; ++c) {
        float w[8];
        const float* p = W + (size_t)n * DD + c * 32 + quad * 8;
        *(float4*)&w[0] = *(const float4*)p;
        *(float4*)&w[4] = *(const float4*)(p + 4);
        split8(w, Whi[tt][c], Wlo[tt][c]);
      }
    }
  };
  auto loadWx = [&](const float* __restrict__ Wx) {
    #pragma unroll
    for (int tt = 0; tt < 2; ++tt) {
      const int n = wid * 32 + 2 * l15 + tt;
      float w[8];
      #pragma unroll
      for (int j = 0; j < 8; ++j) {
        const int k = quad * 8 + j;
        w[j] = (k < CC) ? Wx[(size_t)n * CC + k] : 0.f;
      }
      split8(w, Xhi[tt], Xlo[tt]);
    }
  };
  auto loadBx = [&](const float* __restrict__ bx) {
    #pragma unroll
    for (int tt = 0; tt < 2; ++tt) bxr[tt] = bx[wid * 32 + 2 * l15 + tt];
  };

  // ---------------- init ----------------
  {
    unsigned* z;
    z = (unsigned*)&sm.hcomb[0][0][0];
    for (int i = tid; i < 2 * 16 * HS / 2; i += NTH) z[i] = 0u;
    z = (unsigned*)&sm.xcomb[0][0][0];
    for (int i = tid; i < 4 * 16 * XS / 2; i += NTH) z[i] = 0u;
  }
  loadWh(enc_Wh);
  loadWx(enc_Wx);
  loadBx(enc_bx);
  if (wid == 1) {  // pfB <- x_2 slab (body 0 stages it into slot 2)
    const float* xg = x + ((size_t)2 * NN + n0) * CC;
    pfB0 = xg[lane];
    pfB1 = (lane < 32) ? xg[lane + 64] : 0.f;   // slab is 96 floats: guard OOB
  }
  BAR();
  // direct-stage x_0 -> slot 0, x_1 -> slot 1 (slab is 96 contiguous floats)
  if (tid < 96) {
    #pragma unroll
    for (int s = 0; s < 2; ++s) {
      const float v = x[((size_t)s * NN + n0) * CC + tid];
      const _Float16 h = (_Float16)v;
      sm.xcomb[s][tid / CC][tid % CC] = h;
      sm.xcomb[s][tid / CC + 8][tid % CC] = (_Float16)(v - (float)h);
    }
  }
  BAR();
  // x-term for step 0 into accP
  #pragma unroll
  for (int i = 0; i < 4; ++i) accP[i] = (f32x4){0.f, 0.f, 0.f, 0.f};
  {
    const half8 xa = *(const half8*)&sm.xcomb[0][l15][quad * 8];
    accP[0] = MFMA(xa, Xhi[0], accP[0], 0, 0, 0);
    accP[1] = MFMA(xa, Xlo[0], accP[1], 0, 0, 0);
    accP[2] = MFMA(xa, Xhi[1], accP[2], 0, 0, 0);
    accP[3] = MFMA(xa, Xlo[1], accP[3], 0, 0, 0);
  }

  // ---------------- encoder: skewed, 1 barrier/step ----------------
  auto encCore = [&](int t, f32x4 (&cur)[4], f32x4 (&nxt)[4],
                     float pw0, float pw1) {
    const int rb = t & 1, wb = rb ^ 1;
    const _Float16* hc = &sm.hcomb[rb][l15][0];  // row l15: hi(<8) / lo(>=8)
    #pragma unroll
    for (int c = 0; c < 8; ++c) {
      const half8 a = *(const half8*)(hc + c * 32 + quad * 8);
      cur[0] = MFMA(a, Whi[0][c], cur[0], 0, 0, 0);
      cur[1] = MFMA(a, Wlo[0][c], cur[1], 0, 0, 0);
      cur[2] = MFMA(a, Whi[1][c], cur[2], 0, 0, 0);
      cur[3] = MFMA(a, Wlo[1][c], cur[3], 0, 0, 0);
    }
    // next step's x-term (slot t+1 published >=1 barrier ago)
    #pragma unroll
    for (int i = 0; i < 4; ++i) nxt[i] = (f32x4){0.f, 0.f, 0.f, 0.f};
    if (t + 1 < TT) {
      const int xs = (t + 1) & 3;
      const half8 xa = *(const half8*)&sm.xcomb[xs][l15][quad * 8];
      nxt[0] = MFMA(xa, Xhi[0], nxt[0], 0, 0, 0);
      nxt[1] = MFMA(xa, Xlo[0], nxt[1], 0, 0, 0);
      nxt[2] = MFMA(xa, Xhi[1], nxt[2], 0, 0, 0);
      nxt[3] = MFMA(xa, Xlo[1], nxt[3], 0, 0, 0);
    }
    // epilogue: hi/lo-row merge (xor32), bias, relu, packed split, write
    const int colh = wid * 32 + 2 * l15;
    #pragma unroll
    for (int r = 0; r < 4; ++r) {
      const float e0 = cur[0][r] + cur[1][r];
      const float e1 = cur[2][r] + cur[3][r];
      const float f0 = e0 + __shfl_xor(e0, 32);
      const float f1 = e1 + __shfl_xor(e1, 32);
      const float v0 = fmaxf(f0 + bxr[0], 0.f);
      const float v1 = fmaxf(f1 + bxr[1], 0.f);
      unsigned hw, lw;
      packpair(v0, v1, hw, lw);
      const int p = (quad & 1) * 4 + r;              // batch row 0..7
      const int row = p + 8 * (quad >> 1);           // hi rows 0-7, lo rows 8-15
      *(unsigned*)&sm.hcomb[wb][row][colh] = (quad >> 1) ? lw : hw;
    }
    // stage x_{t+2} into slot (t+2)&3 (regs issued one body ago)
    if (wid == 1) {
      const int xw = (t + 2) & 3;
      #pragma unroll
      for (int j = 0; j < 2; ++j) {
        const int i = lane + 64 * j;
        if (i < 96) {
          const float vv = j ? pw1 : pw0;
          const _Float16 hx = (_Float16)vv;
          sm.xcomb[xw][i / CC][i % CC] = hx;
          sm.xcomb[xw][i / CC + 8][i % CC] = (_Float16)(vv - (float)hx);
        }
      }
    }
    BAR();
  };

  auto encBody = [&](int t, auto IAc) {
    constexpr bool IA = decltype(IAc)::value;
    if (wid == 1) {  // issue pf regs for x_{t+3} (96-float slab: guard OOB)
      const int tp = (t + 3 < TT) ? (t + 3) : (TT - 1);
      const float* xg = x + ((size_t)tp * NN + n0) * CC;
      const float v0 = xg[lane];
      const float v1 = (lane < 32) ? xg[lane + 64] : 0.f;
      if constexpr (IA) { pfA0 = v0; pfA1 = v1; }
      else              { pfB0 = v0; pfB1 = v1; }
    }
    if constexpr (IA) encCore(t, accP, accQ, pfB0, pfB1);
    else              encCore(t, accQ, accP, pfA0, pfA1);
  };

  for (int t = 0; t < TT; t += 2) {
    encBody(t, TrueC{});
    encBody(t + 1, FalseC{});
  }
  // encoder final h now in hcomb[0]

  // ---------------- decoder setup ----------------
  loadWh(dec_Wh);
  loadWx(dec_Wx);
  loadBx(dec_bx);
  float by4[4];
  #pragma unroll
  for (int j = 0; j < 4; ++j) {
    const int o = quad * 4 + j;
    by4[j] = (o < KD) ? dec_by[o] : 0.f;
  }
  half8 wyh, wyl;  // dec_Wy B-fragment for THIS wave's k-chunk (registers)
  {
    float w[8];
    if (l15 < KD) {
      const float* p = dec_Wy + (size_t)l15 * DD + wid * 32 + quad * 8;
      *(float4*)&w[0] = *(const float4*)p;
      *(float4*)&w[4] = *(const float4*)(p + 4);
    } else {
      #pragma unroll
      for (int j = 0; j < 8; ++j) w[j] = 0.f;
    }
    split8(w, wyh, wyl);
  }
  // sos one-hot A-fragment: rows 0-7 one-hot col 10, rows 8-15 (lo) zero
  half8 aX;
  #pragma unroll
  for (int j = 0; j < 8; ++j)
    aX[j] = (_Float16)((l15 < 8 && quad * 8 + j == CC - 2) ? 1.f : 0.f);
  BAR();

  // ---------------- decoder: ONE barrier/step ----------------
  for (int t = 0; t < TT; ++t) {
    const int rb = t & 1, wb = rb ^ 1, pb = t & 1;
    f32x4 cur[4];
    #pragma unroll
    for (int i = 0; i < 4; ++i) cur[i] = (f32x4){0.f, 0.f, 0.f, 0.f};
    // x-term from in-register one-hot sos
    cur[0] = MFMA(aX, Xhi[0], cur[0], 0, 0, 0);
    cur[1] = MFMA(aX, Xlo[0], cur[1], 0, 0, 0);
    cur[2] = MFMA(aX, Xhi[1], cur[2], 0, 0, 0);
    cur[3] = MFMA(aX, Xlo[1], cur[3], 0, 0, 0);
    const _Float16* hc = &sm.hcomb[rb][l15][0];
    #pragma unroll
    for (int c = 0; c < 8; ++c) {
      const half8 a = *(const half8*)(hc + c * 32 + quad * 8);
      cur[0] = MFMA(a, Whi[0][c], cur[0], 0, 0, 0);
      cur[1] = MFMA(a, Wlo[0][c], cur[1], 0, 0, 0);
      cur[2] = MFMA(a, Whi[1][c], cur[2], 0, 0, 0);
      cur[3] = MFMA(a, Wlo[1][c], cur[3], 0, 0, 0);
    }
    const int colh = wid * 32 + 2 * l15;
    #pragma unroll
    for (int r = 0; r < 4; ++r) {
      const float e0 = cur[0][r] + cur[1][r];
      const float e1 = cur[2][r] + cur[3][r];
      const float f0 = e0 + __shfl_xor(e0, 32);
      const float f1 = e1 + __shfl_xor(e1, 32);
      const float v0 = fmaxf(f0 + bxr[0], 0.f);
      const float v1 = fmaxf(f1 + bxr[1], 0.f);
      unsigned hw, lw;
      packpair(v0, v1, hw, lw);
      const int p = (quad & 1) * 4 + r;
      const int row = p + 8 * (quad >> 1);
      *(unsigned*)&sm.hcomb[wb][row][colh] = (quad >> 1) ? lw : hw;
    }
    // y-partial from OWN just-written 32-col slice (this wave wrote all 16
    // combined rows of cols [32wid,32wid+32))
    asm volatile("s_waitcnt lgkmcnt(0)" ::: "memory");
    const half8 ya = *(const half8*)&sm.hcomb[wb][l15][wid * 32 + quad * 8];
    f32x4 y0 = {0.f,0.f,0.f,0.f}, y1 = {0.f,0.f,0.f,0.f};
    y0 = MFMA(ya, wyh, y0, 0, 0, 0);
    y1 = MFMA(ya, wyl, y1, 0, 0, 0);
    // merge hi/lo rows, publish partials (quads 0,1 write rows 0-7)
    #pragma unroll
    for (int r = 0; r < 4; ++r) {
      const float e = y0[r] + y1[r];
      const float f = e + __shfl_xor(e, 32);
      if (quad < 2) sm.part2[pb][wid][(quad & 1) * 4 + r][l15] = f;
    }
    BAR();  // h_t published + all 8 partials visible
    // every wave: reduce 8 partials for (row=l15&7, classes quad*4..+3)
    f32x4 ys = *(const f32x4*)&sm.part2[pb][0][l15 & 7][quad * 4];
    #pragma unroll
    for (int w = 1; w < 8; ++w)
      ys += *(const f32x4*)&sm.part2[pb][w][l15 & 7][quad * 4];
    float yv[4];
    #pragma unroll
    for (int j = 0; j < 4; ++j) yv[j] = ys[j] + by4[j];
    if (wid == 0 && l15 < NB && quad < 3) {  // single-writer out store, f32x4
      float4 st; st.x = yv[0]; st.y = yv[1]; st.z = yv[2]; st.w = yv[3];
      *(float4*)&out[((size_t)t * NN + n0 + l15) * KD + quad * 4] = st;
    }
    // in-lane argmax over this lane's 4 classes (ascending -> first-max kept)
    float v = -1e30f; int io = 0;
    #pragma unroll
    for (int j = 0; j < 4; ++j) {
      const int o = quad * 4 + j;
      const float cv = (o < KD) ? yv[j] : -1e30f;
      const bool take = cv > v;
      io = take ? o : io;
      v  = take ? cv : v;
    }
    // merge across the 4 quads; np first-max tie-break
    #pragma unroll
    for (int d = 16; d < 64; d <<= 1) {
      const float ov = __shfl_xor(v, d);
      const int   oi = __shfl_xor(io, d);
      const bool take = (ov > v) || (ov == v && oi < io);
      v  = take ? ov : v;
      io = take ? oi : io;
    }
    // io = argmax for batch row l15&7 -> rebuild one-hot A frag (lo rows zero)
    #pragma unroll
    for (int j = 0; j < 8; ++j)
      aX[j] = (_Float16)((l15 < 8 && quad * 8 + j == io) ? 1.f : 0.f);
  }
}

extern "C" void kernel_launch(void* const* d_in, const int* in_sizes, int n_in,
                              void* d_out, int out_size, void* d_ws, size_t ws_size,
                              hipStream_t stream) {
  (void)in_sizes; (void)n_in; (void)d_ws; (void)ws_size; (void)out_size;
  const float* x      = (const float*)d_in[0];
  const float* enc_Wx = (const float*)d_in[1];
  const float* enc_bx = (const float*)d_in[2];
  const float* enc_Wh = (const float*)d_in[3];
  // d_in[4] enc_Wy, d_in[5] enc_by: computed-but-discarded in the reference
  const float* dec_Wx = (const float*)d_in[6];
  const float* dec_bx = (const float*)d_in[7];
  const float* dec_Wh = (const float*)d_in[8];
  const float* dec_Wy = (const float*)d_in[9];
  const float* dec_by = (const float*)d_in[10];
  float* outp = (float*)d_out;

  seq2seq_kernel<<<NN / NB, NTH, 0, stream>>>(
      x, enc_Wx, enc_bx, enc_Wh, dec_Wx, dec_bx, dec_Wh, dec_Wy, dec_by, outp);
}

// Round 9
// 1080.844 us; speedup vs baseline: 5.0274x; 5.0274x over previous
//
#include <hip/hip_runtime.h>
#include <cstdint>
#include <cstddef>

#define TT 256
#define NN 4096
#define CC 12
#define DD 256
#define KD 12
#define NB 16
#define NTH 512
#define HS 264   // halfs per h row: 256 + 8 pad (rows 16B-aligned)
#define XS 40    // halfs per x row: 32 + 8 pad

typedef _Float16 half8 __attribute__((ext_vector_type(8)));
typedef __fp16 fp16x2 __attribute__((ext_vector_type(2)));
typedef float f32x4 __attribute__((ext_vector_type(4)));
#define MFMA __builtin_amdgcn_mfma_f32_16x16x32_f16

struct FalseC { static constexpr bool value = false; };
struct TrueC  { static constexpr bool value = true;  };

// LDS: 33,792 (h planes) + 10,240 (4 x slots) = 44,032 B (part2 deleted)
struct alignas(16) SM {
  _Float16 hhi[2][NB][HS];    // h hi plane, double-buffered
  _Float16 hlo[2][NB][HS];    // h lo plane
  _Float16 xhi[4][NB][XS];    // x_t slots (4-deep, skewed prefetch)
  _Float16 xlo[4][NB][XS];
};

__device__ __forceinline__ void split8(const float* w, half8& hi, half8& lo) {
  #pragma unroll
  for (int j = 0; j < 8; ++j) {
    _Float16 h = (_Float16)w[j];
    hi[j] = h;
    lo[j] = (_Float16)(w[j] - (float)h);
  }
}

// packed hi/lo split: pkrtz(v0,v1) -> hi word; lo = v - f32(hi) -> lo word
__device__ __forceinline__ void packpair(float v0, float v1,
                                         unsigned& hw, unsigned& lw) {
  union { fp16x2 v; unsigned u; } a, b;
  a.v = __builtin_amdgcn_cvt_pkrtz(v0, v1);
  const float r0 = (float)a.v[0], r1 = (float)a.v[1];
  b.v = __builtin_amdgcn_cvt_pkrtz(v0 - r0, v1 - r1);
  hw = a.u; lw = b.u;
}

// Raw barrier, R1-proven form: drain LDS only (global ops stay in flight),
// builtin convergent s_barrier, sched_barrier pins order (rule #18).
__device__ __forceinline__ void BAR() {
  asm volatile("s_waitcnt lgkmcnt(0)" ::: "memory");
  __builtin_amdgcn_s_barrier();
  __builtin_amdgcn_sched_barrier(0);
}

__global__ __launch_bounds__(NTH, 2)
void seq2seq_kernel(const float* __restrict__ x,
                    const float* __restrict__ enc_Wx,
                    const float* __restrict__ enc_bx,
                    const float* __restrict__ enc_Wh,
                    const float* __restrict__ dec_Wx,
                    const float* __restrict__ dec_bx,
                    const float* __restrict__ dec_Wh,
                    const float* __restrict__ dec_Wy,
                    const float* __restrict__ dec_by,
                    float* __restrict__ out)
{
  __shared__ SM sm;
  const int tid  = (int)threadIdx.x;
  const int wid  = tid >> 6;
  const int lane = tid & 63;
  const int l15  = lane & 15;
  const int quad = lane >> 4;
  const int n0   = (int)blockIdx.x * NB;

  half8 Whi[2][8], Wlo[2][8];   // Wh B-fragments (reg-resident), persistent
  half8 Xhi[2], Xlo[2];         // Wx B-fragments (K=32 padded chunk)
  float bxr[2];
  // two prefetch register sets; body t issues x_{t+3}, body t+1 writes it
  float pfA0 = 0.f, pfA1 = 0.f, pfA2 = 0.f;
  float pfB0 = 0.f, pfB1 = 0.f, pfB2 = 0.f;
  // two accumulator sets: cur carries this step's x-term (pre-accumulated),
  // nxt receives next step's x-term pre-barrier.
  f32x4 accP[4], accQ[4];

  // B column mapping: n = wid*32 + 2*l15 + tt (lane's two cols adjacent ->
  // packed b32 h-writes, 2 lanes/bank = free).
  auto loadWh = [&](const float* __restrict__ W) {
    #pragma unroll
    for (int tt = 0; tt < 2; ++tt) {
      const int n = wid * 32 + 2 * l15 + tt;
      #pragma unroll
      for (int c = 0; c < 8; ++c) {
        float w[8];
        const float* p = W + (size_t)n * DD + c * 32 + quad * 8;
        *(float4*)&w[0] = *(const float4*)p;
        *(float4*)&w[4] = *(const float4*)(p + 4);
        split8(w, Whi[tt][c], Wlo[tt][c]);
      }
    }
  };
  auto loadWx = [&](const float* __restrict__ Wx) {
    #pragma unroll
    for (int tt = 0; tt < 2; ++tt) {
      const int n = wid * 32 + 2 * l15 + tt;
      float w[8];
      #pragma unroll
      for (int j = 0; j < 8; ++j) {
        const int k = quad * 8 + j;
        w[j] = (k < CC) ? Wx[(size_t)n * CC + k] : 0.f;
      }
      split8(w, Xhi[tt], Xlo[tt]);
    }
  };
  auto loadBx = [&](const float* __restrict__ bx) {
    #pragma unroll
    for (int tt = 0; tt < 2; ++tt) bxr[tt] = bx[wid * 32 + 2 * l15 + tt];
  };

  // ---------------- init ----------------
  {
    unsigned* z;
    z = (unsigned*)&sm.hhi[0][0][0];
    for (int i = tid; i < NB * HS / 2; i += NTH) z[i] = 0u;
    z = (unsigned*)&sm.hlo[0][0][0];
    for (int i = tid; i < NB * HS / 2; i += NTH) z[i] = 0u;
    z = (unsigned*)&sm.xhi[0][0][0];
    for (int i = tid; i < 4 * NB * XS / 2; i += NTH) z[i] = 0u;
    z = (unsigned*)&sm.xlo[0][0][0];
    for (int i = tid; i < 4 * NB * XS / 2; i += NTH) z[i] = 0u;
  }
  loadWh(enc_Wh);
  loadWx(enc_Wx);
  loadBx(enc_bx);
  if (wid == 1) {  // pfB <- x_2 (body 0 stages it into slot 2)
    const float* xg = x + ((size_t)2 * NN + n0) * CC;
    pfB0 = xg[lane]; pfB1 = xg[lane + 64]; pfB2 = xg[lane + 128];
  }
  BAR();
  // direct-stage x_0 -> slot 0, x_1 -> slot 1
  #pragma unroll
  for (int s = 0; s < 2; ++s) {
    if (tid < NB * CC) {
      const float v = x[((size_t)s * NN + n0) * CC + tid];
      const _Float16 h = (_Float16)v;
      sm.xhi[s][tid / CC][tid % CC] = h;
      sm.xlo[s][tid / CC][tid % CC] = (_Float16)(v - (float)h);
    }
  }
  BAR();
  // x-term for step 0 into accP
  #pragma unroll
  for (int i = 0; i < 4; ++i) accP[i] = (f32x4){0.f, 0.f, 0.f, 0.f};
  {
    const half8 xh = *(const half8*)&sm.xhi[0][l15][quad * 8];
    const half8 xl = *(const half8*)&sm.xlo[0][l15][quad * 8];
    accP[0] = MFMA(xh, Xhi[0], accP[0], 0, 0, 0);
    accP[1] = MFMA(xh, Xhi[1], accP[1], 0, 0, 0);
    accP[2] = MFMA(xl, Xhi[0], accP[2], 0, 0, 0);
    accP[3] = MFMA(xl, Xhi[1], accP[3], 0, 0, 0);
    accP[2] = MFMA(xh, Xlo[0], accP[2], 0, 0, 0);
    accP[3] = MFMA(xh, Xlo[1], accP[3], 0, 0, 0);
  }

  // ---------------- encoder: skewed, 1 barrier/step (R5-proven) ----------------
  auto encCore = [&](int t, f32x4 (&cur)[4], f32x4 (&nxt)[4],
                     float pw0, float pw1, float pw2) {
    const int rb = t & 1, wb = rb ^ 1;
    const _Float16* hh = &sm.hhi[rb][l15][0];
    const _Float16* hl = &sm.hlo[rb][l15][0];
    #pragma unroll
    for (int c = 0; c < 8; ++c) {
      const half8 ahi = *(const half8*)(hh + c * 32 + quad * 8);
      const half8 alo = *(const half8*)(hl + c * 32 + quad * 8);
      cur[0] = MFMA(ahi, Whi[0][c], cur[0], 0, 0, 0);
      cur[1] = MFMA(ahi, Whi[1][c], cur[1], 0, 0, 0);
      cur[2] = MFMA(alo, Whi[0][c], cur[2], 0, 0, 0);
      cur[3] = MFMA(alo, Whi[1][c], cur[3], 0, 0, 0);
      cur[0] = MFMA(ahi, Wlo[0][c], cur[0], 0, 0, 0);
      cur[1] = MFMA(ahi, Wlo[1][c], cur[1], 0, 0, 0);
    }
    // next step's x-term (slot t+1 published >=1 barrier ago)
    #pragma unroll
    for (int i = 0; i < 4; ++i) nxt[i] = (f32x4){0.f, 0.f, 0.f, 0.f};
    if (t + 1 < TT) {
      const int xs = (t + 1) & 3;
      const half8 xh = *(const half8*)&sm.xhi[xs][l15][quad * 8];
      const half8 xl = *(const half8*)&sm.xlo[xs][l15][quad * 8];
      nxt[0] = MFMA(xh, Xhi[0], nxt[0], 0, 0, 0);
      nxt[1] = MFMA(xh, Xhi[1], nxt[1], 0, 0, 0);
      nxt[2] = MFMA(xl, Xhi[0], nxt[2], 0, 0, 0);
      nxt[3] = MFMA(xl, Xhi[1], nxt[3], 0, 0, 0);
      nxt[2] = MFMA(xh, Xlo[0], nxt[2], 0, 0, 0);
      nxt[3] = MFMA(xh, Xlo[1], nxt[3], 0, 0, 0);
    }
    // epilogue: merge + bias + relu + packed hi/lo split, write h_{t+1}
    const int colh = wid * 32 + 2 * l15;
    #pragma unroll
    for (int r = 0; r < 4; ++r) {
      const int m = quad * 4 + r;
      const float v0 = fmaxf(cur[0][r] + cur[2][r] + bxr[0], 0.f);
      const float v1 = fmaxf(cur[1][r] + cur[3][r] + bxr[1], 0.f);
      unsigned hw, lw;
      packpair(v0, v1, hw, lw);
      *(unsigned*)&sm.hhi[wb][m][colh] = hw;
      *(unsigned*)&sm.hlo[wb][m][colh] = lw;
    }
    // stage x_{t+2} into slot (t+2)&3 (regs issued one body ago)
    if (wid == 1) {
      const int xw = (t + 2) & 3;
      #pragma unroll
      for (int j = 0; j < 3; ++j) {
        const int i = lane + 64 * j;
        const float vv = (j == 0) ? pw0 : (j == 1) ? pw1 : pw2;
        const _Float16 hx = (_Float16)vv;
        sm.xhi[xw][i / CC][i % CC] = hx;
        sm.xlo[xw][i / CC][i % CC] = (_Float16)(vv - (float)hx);
      }
    }
    BAR();
  };

  auto encBody = [&](int t, auto IAc) {
    constexpr bool IA = decltype(IAc)::value;
    if (wid == 1) {  // issue pf regs for x_{t+3}
      const int tp = (t + 3 < TT) ? (t + 3) : (TT - 1);
      const float* xg = x + ((size_t)tp * NN + n0) * CC;
      if constexpr (IA) { pfA0 = xg[lane]; pfA1 = xg[lane + 64]; pfA2 = xg[lane + 128]; }
      else              { pfB0 = xg[lane]; pfB1 = xg[lane + 64]; pfB2 = xg[lane + 128]; }
    }
    if constexpr (IA) encCore(t, accP, accQ, pfB0, pfB1, pfB2);
    else              encCore(t, accQ, accP, pfA0, pfA1, pfA2);
  };

  for (int t = 0; t < TT; t += 2) {
    encBody(t, TrueC{});
    encBody(t + 1, FalseC{});
  }
  // encoder final h = h(0)_dec now in planes[0]

  // ---------------- decoder setup ----------------
  loadWh(dec_Wh);
  loadWx(dec_Wx);
  loadBx(dec_bx);
  const float byv = (l15 < KD) ? dec_by[l15] : 0.f;
  // dec_Wy hi-plane B-fragments for ALL 8 k-chunks (32 VGPR):
  // lane holds Wy[n=l15][k=c*32+quad*8+j], zero for n>=KD
  half8 Wy8[8];
  #pragma unroll
  for (int c = 0; c < 8; ++c) {
    float w[8];
    if (l15 < KD) {
      const float* p = dec_Wy + (size_t)l15 * DD + c * 32 + quad * 8;
      *(float4*)&w[0] = *(const float4*)p;
      *(float4*)&w[4] = *(const float4*)(p + 4);
    } else {
      #pragma unroll
      for (int j = 0; j < 8; ++j) w[j] = 0.f;
    }
    #pragma unroll
    for (int j = 0; j < 8; ++j) Wy8[c][j] = (_Float16)w[j];
  }
  BAR();

  // ---------------- decoder: ONE barrier/step, fused y ----------------
  // Step t: A = h(t) (buf t&1). The c-loop accumulates BOTH the h-recurrence
  // (into cur accs) and y(t-1) = h(t)·Wy (into yac, reusing the loaded A
  // fragments -> zero extra LDS). argmax(y(t-1)) -> sos_t feeds this step's
  // own x-term MFMAs. No part2, no 2nd barrier, no mid-step drain.
  for (int t = 0; t < TT; ++t) {
    const int rb = t & 1, wb = rb ^ 1;
    f32x4 aA0 = {0.f,0.f,0.f,0.f}, aA1 = {0.f,0.f,0.f,0.f};
    f32x4 aB0 = {0.f,0.f,0.f,0.f}, aB1 = {0.f,0.f,0.f,0.f};
    f32x4 yac = {0.f,0.f,0.f,0.f};
    const _Float16* hh = &sm.hhi[rb][l15][0];
    const _Float16* hl = &sm.hlo[rb][l15][0];
    #pragma unroll
    for (int c = 0; c < 8; ++c) {
      const half8 ahi = *(const half8*)(hh + c * 32 + quad * 8);
      const half8 alo = *(const half8*)(hl + c * 32 + quad * 8);
      aA0 = MFMA(ahi, Whi[0][c], aA0, 0, 0, 0);
      aA1 = MFMA(ahi, Whi[1][c], aA1, 0, 0, 0);
      aB0 = MFMA(alo, Whi[0][c], aB0, 0, 0, 0);
      aB1 = MFMA(alo, Whi[1][c], aB1, 0, 0, 0);
      aA0 = MFMA(ahi, Wlo[0][c], aA0, 0, 0, 0);
      aA1 = MFMA(ahi, Wlo[1][c], aA1, 0, 0, 0);
      yac = MFMA(ahi, Wy8[c], yac, 0, 0, 0);
      yac = MFMA(alo, Wy8[c], yac, 0, 0, 0);
    }
    // y(t-1) complete in-register: yac[r] = y[row quad*4+r][class l15]
    int g;
    if (t == 0) {
      g = CC - 2;  // sos0: one-hot column 10, all rows
    } else {
      float vr[4]; int ir[4];
      #pragma unroll
      for (int r = 0; r < 4; ++r) {
        vr[r] = (l15 < KD) ? yac[r] + byv : -1e30f;
        ir[r] = l15;
      }
      if (wid == 0 && l15 < KD) {  // store out row t-1, fire-and-forget
        #pragma unroll
        for (int r = 0; r < 4; ++r)
          out[((size_t)(t - 1) * NN + n0 + quad * 4 + r) * KD + l15] =
              yac[r] + byv;
      }
      // argmax over classes (16 lanes of each quad-group); np first-max
      #pragma unroll
      for (int d = 1; d < 16; d <<= 1) {
        #pragma unroll
        for (int r = 0; r < 4; ++r) {
          const float ov = __shfl_xor(vr[r], d);
          const int   oi = __shfl_xor(ir[r], d);
          const bool take = (ov > vr[r]) || (ov == vr[r] && oi < ir[r]);
          vr[r] = take ? ov : vr[r];
          ir[r] = take ? oi : ir[r];
        }
      }
      // redistribute: lane needs argmax of row l15 (= quad' l15>>2, r' l15&3)
      const int rsel = l15 & 3;
      const int gsel = rsel == 0 ? ir[0] : rsel == 1 ? ir[1]
                     : rsel == 2 ? ir[2] : ir[3];
      g = __shfl(gsel, ((l15 >> 2) << 4) | l15);
    }
    // one-hot A fragment for row l15, column g
    half8 aX;
    #pragma unroll
    for (int j = 0; j < 8; ++j)
      aX[j] = (_Float16)((quad * 8 + j == g) ? 1.f : 0.f);
    // x-term (exact in f16 -> no lo A plane)
    aA0 = MFMA(aX, Xhi[0], aA0, 0, 0, 0);
    aA1 = MFMA(aX, Xhi[1], aA1, 0, 0, 0);
    aB0 = MFMA(aX, Xlo[0], aB0, 0, 0, 0);
    aB1 = MFMA(aX, Xlo[1], aB1, 0, 0, 0);
    // epilogue: merge + bias + relu + packed split, write h(t+1)
    const int colh = wid * 32 + 2 * l15;
    #pragma unroll
    for (int r = 0; r < 4; ++r) {
      const int m = quad * 4 + r;
      const float v0 = fmaxf(aA0[r] + aB0[r] + bxr[0], 0.f);
      const float v1 = fmaxf(aA1[r] + aB1[r] + bxr[1], 0.f);
      unsigned hw, lw;
      packpair(v0, v1, hw, lw);
      *(unsigned*)&sm.hhi[wb][m][colh] = hw;
      *(unsigned*)&sm.hlo[wb][m][colh] = lw;
    }
    BAR();
  }
  // final pass: y(TT-1) = h(TT)·Wy; h(TT) is in buf (TT-1&1)^1 = 0
  {
    f32x4 yac = {0.f,0.f,0.f,0.f};
    const _Float16* hh = &sm.hhi[0][l15][0];
    const _Float16* hl = &sm.hlo[0][l15][0];
    #pragma unroll
    for (int c = 0; c < 8; ++c) {
      const half8 ahi = *(const half8*)(hh + c * 32 + quad * 8);
      const half8 alo = *(const half8*)(hl + c * 32 + quad * 8);
      yac = MFMA(ahi, Wy8[c], yac, 0, 0, 0);
      yac = MFMA(alo, Wy8[c], yac, 0, 0, 0);
    }
    if (wid == 0 && l15 < KD) {
      #pragma unroll
      for (int r = 0; r < 4; ++r)
        out[((size_t)(TT - 1) * NN + n0 + quad * 4 + r) * KD + l15] =
            yac[r] + byv;
    }
  }
}

extern "C" void kernel_launch(void* const* d_in, const int* in_sizes, int n_in,
                              void* d_out, int out_size, void* d_ws, size_t ws_size,
                              hipStream_t stream) {
  (void)in_sizes; (void)n_in; (void)d_ws; (void)ws_size; (void)out_size;
  const float* x      = (const float*)d_in[0];
  const float* enc_Wx = (const float*)d_in[1];
  const float* enc_bx = (const float*)d_in[2];
  const float* enc_Wh = (const float*)d_in[3];
  // d_in[4] enc_Wy, d_in[5] enc_by: computed-but-discarded in the reference
  const float* dec_Wx = (const float*)d_in[6];
  const float* dec_bx = (const float*)d_in[7];
  const float* dec_Wh = (const float*)d_in[8];
  const float* dec_Wy = (const float*)d_in[9];
  const float* dec_by = (const float*)d_in[10];
  float* outp = (float*)d_out;

  seq2seq_kernel<<<NN / NB, NTH, 0, stream>>>(
      x, enc_Wx, enc_bx, enc_Wh, dec_Wx, dec_bx, dec_Wh, dec_Wy, dec_by, outp);
}

// Round 10
// 790.401 us; speedup vs baseline: 6.8748x; 1.3675x over previous
//
#include <hip/hip_runtime.h>
#include <cstdint>
#include <cstddef>

#define TT 256
#define NN 4096
#define CC 12
#define DD 256
#define KD 12
#define NB 16
#define NTH 512
#define HS 264   // halfs per h row: 256 + 8 pad (rows 16B-aligned)
#define XS 40    // halfs per x row: 32 + 8 pad
#define YS 20    // floats per part2 row: 16 + 4 pad (rows 16B-aligned)

typedef _Float16 half8 __attribute__((ext_vector_type(8)));
typedef __fp16 fp16x2 __attribute__((ext_vector_type(2)));
typedef float f32x4 __attribute__((ext_vector_type(4)));
#define MFMA __builtin_amdgcn_mfma_f32_16x16x32_f16

struct FalseC { static constexpr bool value = false; };
struct TrueC  { static constexpr bool value = true;  };

// LDS: 33,792 (h planes) + 10,240 (4 x slots) + 20,480 (part2 x2) = 64,512 B
struct alignas(16) SM {
  _Float16 hhi[2][NB][HS];    // h hi plane, double-buffered
  _Float16 hlo[2][NB][HS];    // h lo plane
  _Float16 xhi[4][NB][XS];    // x_t slots (4-deep, skewed prefetch)
  _Float16 xlo[4][NB][XS];
  float    part2[2][8][NB][YS];  // decoder y partials [buf][wave][row][class]
};

__device__ __forceinline__ void split8(const float* w, half8& hi, half8& lo) {
  #pragma unroll
  for (int j = 0; j < 8; ++j) {
    _Float16 h = (_Float16)w[j];
    hi[j] = h;
    lo[j] = (_Float16)(w[j] - (float)h);
  }
}

// packed hi/lo split: pkrtz(v0,v1) -> hi word; lo = v - f32(hi) -> lo word
__device__ __forceinline__ void packpair(float v0, float v1,
                                         unsigned& hw, unsigned& lw) {
  union { fp16x2 v; unsigned u; } a, b;
  a.v = __builtin_amdgcn_cvt_pkrtz(v0, v1);
  const float r0 = (float)a.v[0], r1 = (float)a.v[1];
  b.v = __builtin_amdgcn_cvt_pkrtz(v0 - r0, v1 - r1);
  hw = a.u; lw = b.u;
}

// Raw barrier, R1-proven form: drain LDS only (global ops stay in flight),
// builtin convergent s_barrier, sched_barrier pins order (rule #18).
__device__ __forceinline__ void BAR() {
  asm volatile("s_waitcnt lgkmcnt(0)" ::: "memory");
  __builtin_amdgcn_s_barrier();
  __builtin_amdgcn_sched_barrier(0);
}

__global__ __launch_bounds__(NTH, 2)
void seq2seq_kernel(const float* __restrict__ x,
                    const float* __restrict__ enc_Wx,
                    const float* __restrict__ enc_bx,
                    const float* __restrict__ enc_Wh,
                    const float* __restrict__ dec_Wx,
                    const float* __restrict__ dec_bx,
                    const float* __restrict__ dec_Wh,
                    const float* __restrict__ dec_Wy,
                    const float* __restrict__ dec_by,
                    float* __restrict__ out)
{
  __shared__ SM sm;
  const int tid  = (int)threadIdx.x;
  const int wid  = tid >> 6;
  const int lane = tid & 63;
  const int l15  = lane & 15;
  const int quad = lane >> 4;
  const int n0   = (int)blockIdx.x * NB;

  half8 Whi[2][8], Wlo[2][8];   // Wh B-fragments (reg-resident), persistent
  half8 Xhi[2], Xlo[2];         // Wx B-fragments (K=32 padded chunk)
  float bxr[2];
  // x-prefetch distributed over waves 0-2 (1 x 64-float chunk each) to avoid
  // a single straggler wave pacing the per-step barrier. Two register sets.
  float pfA = 0.f, pfB = 0.f;
  // two accumulator sets: cur carries this step's x-term (pre-accumulated),
  // nxt receives next step's x-term pre-barrier.
  f32x4 accP[4], accQ[4];

  // B column mapping: n = wid*32 + 2*l15 + tt (lane's two cols adjacent ->
  // packed b32 h-writes, 2 lanes/bank = free).
  auto loadWh = [&](const float* __restrict__ W) {
    #pragma unroll
    for (int tt = 0; tt < 2; ++tt) {
      const int n = wid * 32 + 2 * l15 + tt;
      #pragma unroll
      for (int c = 0; c < 8; ++c) {
        float w[8];
        const float* p = W + (size_t)n * DD + c * 32 + quad * 8;
        *(float4*)&w[0] = *(const float4*)p;
        *(float4*)&w[4] = *(const float4*)(p + 4);
        split8(w, Whi[tt][c], Wlo[tt][c]);
      }
    }
  };
  auto loadWx = [&](const float* __restrict__ Wx) {
    #pragma unroll
    for (int tt = 0; tt < 2; ++tt) {
      const int n = wid * 32 + 2 * l15 + tt;
      float w[8];
      #pragma unroll
      for (int j = 0; j < 8; ++j) {
        const int k = quad * 8 + j;
        w[j] = (k < CC) ? Wx[(size_t)n * CC + k] : 0.f;
      }
      split8(w, Xhi[tt], Xlo[tt]);
    }
  };
  auto loadBx = [&](const float* __restrict__ bx) {
    #pragma unroll
    for (int tt = 0; tt < 2; ++tt) bxr[tt] = bx[wid * 32 + 2 * l15 + tt];
  };

  // ---------------- init ----------------
  {
    unsigned* z;
    z = (unsigned*)&sm.hhi[0][0][0];
    for (int i = tid; i < NB * HS / 2; i += NTH) z[i] = 0u;
    z = (unsigned*)&sm.hlo[0][0][0];
    for (int i = tid; i < NB * HS / 2; i += NTH) z[i] = 0u;
    z = (unsigned*)&sm.xhi[0][0][0];
    for (int i = tid; i < 4 * NB * XS / 2; i += NTH) z[i] = 0u;
    z = (unsigned*)&sm.xlo[0][0][0];
    for (int i = tid; i < 4 * NB * XS / 2; i += NTH) z[i] = 0u;
  }
  loadWh(enc_Wh);
  loadWx(enc_Wx);
  loadBx(enc_bx);
  if (wid < 3) {  // pfB <- x_2 slab chunk (body 0 stages it into slot 2)
    pfB = x[((size_t)2 * NN + n0) * CC + wid * 64 + lane];
  }
  BAR();
  // direct-stage x_0 -> slot 0, x_1 -> slot 1 (192 floats each)
  #pragma unroll
  for (int s = 0; s < 2; ++s) {
    if (tid < NB * CC) {
      const float v = x[((size_t)s * NN + n0) * CC + tid];
      const _Float16 h = (_Float16)v;
      sm.xhi[s][tid / CC][tid % CC] = h;
      sm.xlo[s][tid / CC][tid % CC] = (_Float16)(v - (float)h);
    }
  }
  BAR();
  // x-term for step 0 into accP
  #pragma unroll
  for (int i = 0; i < 4; ++i) accP[i] = (f32x4){0.f, 0.f, 0.f, 0.f};
  {
    const half8 xh = *(const half8*)&sm.xhi[0][l15][quad * 8];
    const half8 xl = *(const half8*)&sm.xlo[0][l15][quad * 8];
    accP[0] = MFMA(xh, Xhi[0], accP[0], 0, 0, 0);
    accP[1] = MFMA(xh, Xhi[1], accP[1], 0, 0, 0);
    accP[2] = MFMA(xl, Xhi[0], accP[2], 0, 0, 0);
    accP[3] = MFMA(xl, Xhi[1], accP[3], 0, 0, 0);
    accP[2] = MFMA(xh, Xlo[0], accP[2], 0, 0, 0);
    accP[3] = MFMA(xh, Xlo[1], accP[3], 0, 0, 0);
  }

  // ---------------- encoder: skewed, 1 barrier/step (R5-proven) ----------------
  auto encCore = [&](int t, f32x4 (&cur)[4], f32x4 (&nxt)[4], float pw) {
    const int rb = t & 1, wb = rb ^ 1;
    const _Float16* hh = &sm.hhi[rb][l15][0];
    const _Float16* hl = &sm.hlo[rb][l15][0];
    #pragma unroll
    for (int c = 0; c < 8; ++c) {
      const half8 ahi = *(const half8*)(hh + c * 32 + quad * 8);
      const half8 alo = *(const half8*)(hl + c * 32 + quad * 8);
      cur[0] = MFMA(ahi, Whi[0][c], cur[0], 0, 0, 0);
      cur[1] = MFMA(ahi, Whi[1][c], cur[1], 0, 0, 0);
      cur[2] = MFMA(alo, Whi[0][c], cur[2], 0, 0, 0);
      cur[3] = MFMA(alo, Whi[1][c], cur[3], 0, 0, 0);
      cur[0] = MFMA(ahi, Wlo[0][c], cur[0], 0, 0, 0);
      cur[1] = MFMA(ahi, Wlo[1][c], cur[1], 0, 0, 0);
    }
    // next step's x-term (slot t+1 published >=1 barrier ago)
    #pragma unroll
    for (int i = 0; i < 4; ++i) nxt[i] = (f32x4){0.f, 0.f, 0.f, 0.f};
    if (t + 1 < TT) {
      const int xs = (t + 1) & 3;
      const half8 xh = *(const half8*)&sm.xhi[xs][l15][quad * 8];
      const half8 xl = *(const half8*)&sm.xlo[xs][l15][quad * 8];
      nxt[0] = MFMA(xh, Xhi[0], nxt[0], 0, 0, 0);
      nxt[1] = MFMA(xh, Xhi[1], nxt[1], 0, 0, 0);
      nxt[2] = MFMA(xl, Xhi[0], nxt[2], 0, 0, 0);
      nxt[3] = MFMA(xl, Xhi[1], nxt[3], 0, 0, 0);
      nxt[2] = MFMA(xh, Xlo[0], nxt[2], 0, 0, 0);
      nxt[3] = MFMA(xh, Xlo[1], nxt[3], 0, 0, 0);
    }
    // epilogue: merge + bias + relu + packed hi/lo split, write h_{t+1}
    const int colh = wid * 32 + 2 * l15;
    #pragma unroll
    for (int r = 0; r < 4; ++r) {
      const int m = quad * 4 + r;
      const float v0 = fmaxf(cur[0][r] + cur[2][r] + bxr[0], 0.f);
      const float v1 = fmaxf(cur[1][r] + cur[3][r] + bxr[1], 0.f);
      unsigned hw, lw;
      packpair(v0, v1, hw, lw);
      *(unsigned*)&sm.hhi[wb][m][colh] = hw;
      *(unsigned*)&sm.hlo[wb][m][colh] = lw;
    }
    // stage x_{t+2} into slot (t+2)&3 (regs issued one body ago; waves 0-2)
    if (wid < 3) {
      const int xw = (t + 2) & 3;
      const int i = wid * 64 + lane;
      const _Float16 hx = (_Float16)pw;
      sm.xhi[xw][i / CC][i % CC] = hx;
      sm.xlo[xw][i / CC][i % CC] = (_Float16)(pw - (float)hx);
    }
    BAR();
  };

  auto encBody = [&](int t, auto IAc) {
    constexpr bool IA = decltype(IAc)::value;
    if (wid < 3) {  // issue pf reg for x_{t+3} (this wave's 64-float chunk)
      const int tp = (t + 3 < TT) ? (t + 3) : (TT - 1);
      const float v = x[((size_t)tp * NN + n0) * CC + wid * 64 + lane];
      if constexpr (IA) pfA = v;
      else              pfB = v;
    }
    if constexpr (IA) encCore(t, accP, accQ, pfB);
    else              encCore(t, accQ, accP, pfA);
  };

  for (int t = 0; t < TT; t += 2) {
    encBody(t, TrueC{});
    encBody(t + 1, FalseC{});
  }
  // encoder final h now in planes[0]

  // ---------------- decoder setup ----------------
  loadWh(dec_Wh);
  loadWx(dec_Wx);
  loadBx(dec_bx);
  float by4[4];
  #pragma unroll
  for (int j = 0; j < 4; ++j) {
    const int o = quad * 4 + j;
    by4[j] = (o < KD) ? dec_by[o] : 0.f;
  }
  half8 wyh, wyl;  // dec_Wy B-fragment for THIS wave's k-chunk (registers)
  {
    float w[8];
    if (l15 < KD) {
      const float* p = dec_Wy + (size_t)l15 * DD + wid * 32 + quad * 8;
      *(float4*)&w[0] = *(const float4*)p;
      *(float4*)&w[4] = *(const float4*)(p + 4);
    } else {
      #pragma unroll
      for (int j = 0; j < 8; ++j) w[j] = 0.f;
    }
    split8(w, wyh, wyl);
  }
  // sos one-hot A-fragment in registers: column CC-2 = 10
  half8 aX;
  #pragma unroll
  for (int j = 0; j < 8; ++j)
    aX[j] = (_Float16)((quad * 8 + j == CC - 2) ? 1.f : 0.f);
  BAR();

  // ---------------- decoder: ONE barrier/step, no atomics (R5-proven) ----------------
  for (int t = 0; t < TT; ++t) {
    const int rb = t & 1, wb = rb ^ 1, pb = t & 1;
    f32x4 aA0 = {0.f,0.f,0.f,0.f}, aA1 = {0.f,0.f,0.f,0.f};
    f32x4 aB0 = {0.f,0.f,0.f,0.f}, aB1 = {0.f,0.f,0.f,0.f};
    // x-term from in-register one-hot sos (exact in f16 -> no lo A plane)
    aA0 = MFMA(aX, Xhi[0], aA0, 0, 0, 0);
    aA1 = MFMA(aX, Xhi[1], aA1, 0, 0, 0);
    aB0 = MFMA(aX, Xlo[0], aB0, 0, 0, 0);
    aB1 = MFMA(aX, Xlo[1], aB1, 0, 0, 0);
    const _Float16* hh = &sm.hhi[rb][l15][0];
    const _Float16* hl = &sm.hlo[rb][l15][0];
    #pragma unroll
    for (int c = 0; c < 8; ++c) {
      const half8 ahi = *(const half8*)(hh + c * 32 + quad * 8);
      const half8 alo = *(const half8*)(hl + c * 32 + quad * 8);
      aA0 = MFMA(ahi, Whi[0][c], aA0, 0, 0, 0);
      aA1 = MFMA(ahi, Whi[1][c], aA1, 0, 0, 0);
      aB0 = MFMA(alo, Whi[0][c], aB0, 0, 0, 0);
      aB1 = MFMA(alo, Whi[1][c], aB1, 0, 0, 0);
      aA0 = MFMA(ahi, Wlo[0][c], aA0, 0, 0, 0);
      aA1 = MFMA(ahi, Wlo[1][c], aA1, 0, 0, 0);
    }
    const int colh = wid * 32 + 2 * l15;
    #pragma unroll
    for (int r = 0; r < 4; ++r) {
      const int m = quad * 4 + r;
      const float v0 = fmaxf(aA0[r] + aB0[r] + bxr[0], 0.f);
      const float v1 = fmaxf(aA1[r] + aB1[r] + bxr[1], 0.f);
      unsigned hw, lw;
      packpair(v0, v1, hw, lw);
      *(unsigned*)&sm.hhi[wb][m][colh] = hw;
      *(unsigned*)&sm.hlo[wb][m][colh] = lw;
    }
    // y-partial from OWN just-written 32-col slice (no cross-wave dependency)
    asm volatile("s_waitcnt lgkmcnt(0)" ::: "memory");  // own writes -> readable
    const half8 yh8 = *(const half8*)&sm.hhi[wb][l15][wid * 32 + quad * 8];
    const half8 yl8 = *(const half8*)&sm.hlo[wb][l15][wid * 32 + quad * 8];
    f32x4 yp = {0.f,0.f,0.f,0.f};
    yp = MFMA(yh8, wyh, yp, 0, 0, 0);
    yp = MFMA(yl8, wyh, yp, 0, 0, 0);
    yp = MFMA(yh8, wyl, yp, 0, 0, 0);
    // publish partials: yp[r] = y-partial[row quad*4+r][class l15] from wave wid
    #pragma unroll
    for (int r = 0; r < 4; ++r)
      sm.part2[pb][wid][quad * 4 + r][l15] = yp[r];
    BAR();  // h_t published + all 8 partials visible
    // every wave: reduce all 8 partials for (row=l15, classes quad*4..+3)
    f32x4 ys = *(const f32x4*)&sm.part2[pb][0][l15][quad * 4];
    #pragma unroll
    for (int w = 1; w < 8; ++w)
      ys += *(const f32x4*)&sm.part2[pb][w][l15][quad * 4];
    float yv[4];
    #pragma unroll
    for (int j = 0; j < 4; ++j) yv[j] = ys[j] + by4[j];
    if (wid == 0 && quad < 3) {  // single-writer out store, f32x4, fire-and-forget
      float4 st; st.x = yv[0]; st.y = yv[1]; st.z = yv[2]; st.w = yv[3];
      *(float4*)&out[((size_t)t * NN + n0 + l15) * KD + quad * 4] = st;
    }
    // in-lane argmax over this lane's 4 classes (ascending -> first-max kept)
    float v = -1e30f; int io = 0;
    #pragma unroll
    for (int j = 0; j < 4; ++j) {
      const int o = quad * 4 + j;
      const float cv = (o < KD) ? yv[j] : -1e30f;
      const bool take = cv > v;
      io = take ? o : io;
      v  = take ? cv : v;
    }
    // merge across the 4 quads (lane bits 4,5); np first-max tie-break.
    // every lane ends with argmax of ITS row l15 -> feeds aX directly.
    #pragma unroll
    for (int d = 16; d < 64; d <<= 1) {
      const float ov = __shfl_xor(v, d);
      const int   oi = __shfl_xor(io, d);
      const bool take = (ov > v) || (ov == v && oi < io);
      v  = take ? ov : v;
      io = take ? oi : io;
    }
    #pragma unroll
    for (int j = 0; j < 8; ++j)
      aX[j] = (_Float16)((quad * 8 + j == io) ? 1.f : 0.f);
  }
}

extern "C" void kernel_launch(void* const* d_in, const int* in_sizes, int n_in,
                              void* d_out, int out_size, void* d_ws, size_t ws_size,
                              hipStream_t stream) {
  (void)in_sizes; (void)n_in; (void)d_ws; (void)ws_size; (void)out_size;
  const float* x      = (const float*)d_in[0];
  const float* enc_Wx = (const float*)d_in[1];
  const float* enc_bx = (const float*)d_in[2];
  const float* enc_Wh = (const float*)d_in[3];
  // d_in[4] enc_Wy, d_in[5] enc_by: computed-but-discarded in the reference
  const float* dec_Wx = (const float*)d_in[6];
  const float* dec_bx = (const float*)d_in[7];
  const float* dec_Wh = (const float*)d_in[8];
  const float* dec_Wy = (const float*)d_in[9];
  const float* dec_by = (const float*)d_in[10];
  float* outp = (float*)d_out;

  seq2seq_kernel<<<NN / NB, NTH, 0, stream>>>(
      x, enc_Wx, enc_bx, enc_Wh, dec_Wx, dec_bx, dec_Wh, dec_Wy, dec_by, outp);
}